// Round 9
// baseline (180.639 us; speedup 1.0000x reference)
//
#include <hip/hip_runtime.h>
#include <math.h>

typedef unsigned short u16;
typedef unsigned int   u32;
typedef __attribute__((ext_vector_type(8))) short bf16x8;
typedef __attribute__((ext_vector_type(4))) float floatx4;
typedef __attribute__((ext_vector_type(4))) _Float16 halfx4;
typedef __attribute__((ext_vector_type(8))) _Float16 halfx8;
typedef __attribute__((ext_vector_type(2))) unsigned int uintx2;

// B=2, S=2048, D=1024, H=16, Dh=64, M=B*S=4096
#define SEQ 2048
#define DM  1024
#define NH  16
#define DH  64
#define MM  4096
#define QSCALE 0.18033688011112042f   // 0.125 * log2(e), folded into Q

__device__ __forceinline__ u16 f2bf(float f) {
    u32 u = __builtin_bit_cast(u32, f);
    u += 0x7fffu + ((u >> 16) & 1u);
    return (u16)(u >> 16);
}

__device__ __forceinline__ void async16(const void* g, void* l) {
    __builtin_amdgcn_global_load_lds(
        (const __attribute__((address_space(1))) void*)g,
        (__attribute__((address_space(3))) void*)l, 16, 0, 0);
}

// ---------------- prep: fp32 -> bf16 shuffled layout + RoPE table -------------------
// Shuffled layout: tile (rowblk=row/16, ktile=col/32); element [m=lm][k=quad*8+j]
// stored flat at (rowblk*32 + ktile)*512 + lane*8 + j. One dwordx4/lane per fragment.
// First 256 linear blocks additionally fill the RoPE table (2048x32 float2).
__global__ __launch_bounds__(256) void prep_kernel(const float* __restrict__ x,
                                                   const float* __restrict__ w0,
                                                   const float* __restrict__ w1,
                                                   const float* __restrict__ w2,
                                                   const float* __restrict__ w3,
                                                   u16* __restrict__ Xsh,
                                                   u16* __restrict__ Wsh,
                                                   const int* __restrict__ pos,
                                                   float2* __restrict__ tab) {
    const int bid = blockIdx.x, cb = blockIdx.y, tid = threadIdx.x;

    // RoPE table side-job
    int lin = bid * 16 + cb;
    if (lin < 256) {
        int i = lin * 256 + tid;       // 65536 = 2048*32
        int p = i >> 5, d2 = i & 31;
        float freq = __expf(-(float)d2 * (9.2103403719761836f / 32.0f));
        float sv, cv;
        sincosf((float)pos[p] * freq, &sv, &cv);
        tab[i] = make_float2(cv, sv);
    }

    const float* src; u16* dst; int row0;
    if (bid < 64) { src = x; dst = Xsh; row0 = bid * 64; }
    else {
        int wi = (bid - 64) >> 4;
        src = (wi == 0) ? w0 : (wi == 1) ? w1 : (wi == 2) ? w2 : w3;
        dst = Wsh + (size_t)wi * DM * DM;
        row0 = ((bid - 64) & 15) * 64;
    }
    __shared__ __align__(16) u16 t[64 * 64];   // 8-elem chunks XOR-swizzled by row&7
#pragma unroll
    for (int rep = 0; rep < 4; ++rep) {
        int f = rep * 256 + tid;
        int r = f >> 4, c4 = f & 15;
        float4 v = *(const float4*)&src[(size_t)(row0 + r) * DM + cb * 64 + c4 * 4];
        uint2 pk;
        pk.x = (u32)f2bf(v.x) | ((u32)f2bf(v.y) << 16);
        pk.y = (u32)f2bf(v.z) | ((u32)f2bf(v.w) << 16);
        int ch = (c4 >> 1) ^ (r & 7);
        *(uint2*)&t[r * 64 + ch * 8 + (c4 & 1) * 4] = pk;
    }
    __syncthreads();
#pragma unroll
    for (int rep = 0; rep < 2; ++rep) {
        int s = rep * 256 + tid;
        int tile = s >> 6, l = s & 63;
        int mt = tile >> 1, kt = tile & 1, lm = l & 15, quad = l >> 4;
        int m = mt * 16 + lm;
        uint4 v = *(const uint4*)&t[m * 64 + ((kt * 4 + quad) ^ (m & 7)) * 8];
        size_t rowblk = (size_t)(row0 >> 4) + mt;
        size_t ktile  = cb * 2 + kt;
        *(uint4*)&dst[(rowblk * 32 + ktile) * 512 + l * 8] = v;
    }
}

// ---------------- per-z NT GEMM, counted-vmcnt triple-buffer K-loop (T4) ------------
// C_z[M,1024] = A * W_z^T, z = blockIdx.z. Block tile BM x 128 (BM = MREP*32),
// 4 waves (2x2), wave tile (MREP*16) x 64. BK=32, 32 K-steps.
// THREE LDS buffers; per iter: {s_waitcnt vmcnt(LPS); s_barrier} (single asm, memory
// clobber) -> waits ONLY for tile it (tile it+1 stays in flight across the barrier),
// then issue stage(it+2), then MFMA. T4: never vmcnt(0) in the main loop.
// Epilogues: z==0 Q (RoPE+QSCALE, natural bf16); z==1 K (RoPE + LDS-bounce
// transpose -> QK-A-fragment chunks, 32-key-group PERMUTED key order: tile (g,t)
// row lm holds key 32g + (lm>>2)*8 + t*4 + (lm&3), so attn's packed exp pairs feed
// the K=32 f16 PV MFMA with zero cross-lane ops); z==2 V (PV-A-fragment chunks);
// OUTF32 (Wo, MREP=2) writes fp32.
template<int MREP, bool OUTF32>
__global__ __launch_bounds__(256, (MREP == 4) ? 3 : 2)
void gemm_s(const u16* __restrict__ Ash,
            const u16* __restrict__ Wbase,
            u16* __restrict__ qout,
            float* __restrict__ outf,
            _Float16* __restrict__ vtout,
            u16* __restrict__ kout,
            const float2* __restrict__ ropetab) {
    constexpr int BM  = MREP * 32;         // 128 (QKV) or 64 (Wo)
    constexpr int AC  = 2 * MREP;          // A chunks per K-step
    constexpr int APW = AC / 4;            // A chunks staged per wave
    constexpr int STEP = (AC + 8) * 512;   // u16 per LDS buffer
    constexpr int SHN  = 3 * STEP;         // 48KB (QKV; covers 17408-u16 K-scratch) / 36KB (Wo)

    const int z  = blockIdx.z;
    const u16* Wp = Wbase + (size_t)z * (DM * DM);
    const int m0 = blockIdx.x * BM, n0 = blockIdx.y * 128;
    const int tid = threadIdx.x, lane = tid & 63, w = tid >> 6;
    const int wr = w >> 1, wc = w & 1;
    const int lm = lane & 15, quad = lane >> 4;
    const int rb0 = m0 >> 4, cb0 = n0 >> 4;

    __shared__ __align__(16) u16 sh[SHN];

    auto stage = [&](int buf, int it) {
        u16* la = sh + buf * STEP;
        u16* lb = la + AC * 512;
#pragma unroll
        for (int j = 0; j < APW; ++j) {
            int c = w * APW + j;
            async16(Ash + ((size_t)(rb0 + c) * 32 + it) * 512 + lane * 8,
                    &la[c * 512 + lane * 8]);
        }
#pragma unroll
        for (int j = 0; j < 2; ++j) {
            int c = w * 2 + j;
            async16(Wp + ((size_t)(cb0 + c) * 32 + it) * 512 + lane * 8,
                    &lb[c * 512 + lane * 8]);
        }
    };

    floatx4 acc[MREP][4];
    const floatx4 z4 = {0.f, 0.f, 0.f, 0.f};
#pragma unroll
    for (int mt = 0; mt < MREP; ++mt)
#pragma unroll
        for (int nt = 0; nt < 4; ++nt) acc[mt][nt] = z4;

    stage(0, 0);
    stage(1, 1);

    int cur = 0;
    for (int it = 0; it < 32; ++it) {
        // counted wait: tile it landed; tile it+1's loads stay in flight (LPS=APW+2).
        if (it == 31) {
            asm volatile("s_waitcnt vmcnt(0)\n\ts_barrier" ::: "memory");
        } else {
            if constexpr (MREP == 4)
                asm volatile("s_waitcnt vmcnt(4)\n\ts_barrier" ::: "memory");
            else
                asm volatile("s_waitcnt vmcnt(3)\n\ts_barrier" ::: "memory");
        }
        if (it < 30) {
            int pre = cur - 1; if (pre < 0) pre = 2;   // (it+2) % 3
            stage(pre, it + 2);
        }
        const u16* la = sh + cur * STEP;
        const u16* lb = la + AC * 512;
        bf16x8 a[MREP], b[4];
#pragma unroll
        for (int mt = 0; mt < MREP; ++mt)
            a[mt] = *(const bf16x8*)&la[(wr * MREP + mt) * 512 + lane * 8];
#pragma unroll
        for (int nt = 0; nt < 4; ++nt)
            b[nt] = *(const bf16x8*)&lb[(wc * 4 + nt) * 512 + lane * 8];
#pragma unroll
        for (int mt = 0; mt < MREP; ++mt)
#pragma unroll
            for (int nt = 0; nt < 4; ++nt)
                acc[mt][nt] = __builtin_amdgcn_mfma_f32_16x16x32_bf16(
                    a[mt], b[nt], acc[mt][nt], 0, 0, 0);
        ++cur; if (cur == 3) cur = 0;
    }
    __syncthreads();   // all waves done with sh before epilogue reuse (z==1 scratch)

    if constexpr (OUTF32) {
#pragma unroll
        for (int mt = 0; mt < MREP; ++mt)
#pragma unroll
            for (int r = 0; r < 4; ++r) {
                int row = m0 + wr * (MREP * 16) + mt * 16 + quad * 4 + r;
#pragma unroll
                for (int nt = 0; nt < 4; ++nt) {
                    int col = n0 + wc * 64 + nt * 16 + lm;
                    outf[(size_t)row * DM + col] = acc[mt][nt][r];
                }
            }
        return;
    } else {
        if (z == 0) {
            // Q: RoPE + QSCALE, natural bf16 (pair store via lane-parity)
#pragma unroll
            for (int mt = 0; mt < MREP; ++mt)
#pragma unroll
                for (int r = 0; r < 4; ++r) {
                    int row = m0 + wr * (MREP * 16) + mt * 16 + quad * 4 + r;
#pragma unroll
                    for (int nt = 0; nt < 4; ++nt) {
                        int col = n0 + wc * 64 + nt * 16 + lm;
                        float v  = acc[mt][nt][r];
                        float pv = __shfl_xor(v, 1);
                        float2 cs = ropetab[(row & (SEQ - 1)) * 32 + ((col & 63) >> 1)];
                        v = (lm & 1) ? fmaf(pv, cs.y, v * cs.x) : fmaf(v, cs.x, -pv * cs.y);
                        v *= QSCALE;
                        float hv = __shfl_xor(v, 1);
                        if (!(lm & 1)) {
                            u32 pk = (u32)f2bf(v) | ((u32)f2bf(hv) << 16);
                            *(u32*)&qout[(size_t)row * DM + col] = pk;
                        }
                    }
                }
        } else if (z == 1) {
            if constexpr (MREP == 4) {
                // K: RoPE, LDS-bounce transpose into QK A-fragment chunks.
                // Chunk = ((bh*128 + sblk)*2 + ks2), 512 bf16; sblk = 2g+t.
                // PERMUTED: element lane*8+j = K[key = 32g + (lm>>2)*8 + t*4 + (lm&3)]
                //                              [kd = ks2*32 + quad*8 + j].
                u16* t = sh;   // 128 x 136 u16 scratch (union over stage buffers)
#pragma unroll
                for (int mt = 0; mt < MREP; ++mt)
#pragma unroll
                    for (int r = 0; r < 4; ++r) {
                        int rl  = wr * 64 + mt * 16 + quad * 4 + r;
                        int row = m0 + rl;
#pragma unroll
                        for (int nt = 0; nt < 4; ++nt) {
                            int cl  = wc * 64 + nt * 16 + lm;
                            int col = n0 + cl;
                            float v  = acc[mt][nt][r];
                            float pv = __shfl_xor(v, 1);
                            float2 cs = ropetab[(row & (SEQ - 1)) * 32 + ((col & 63) >> 1)];
                            v = (lm & 1) ? fmaf(pv, cs.y, v * cs.x) : fmaf(v, cs.x, -pv * cs.y);
                            t[rl * 136 + cl] = f2bf(v);
                        }
                    }
                __syncthreads();
                {
                    int bb = m0 >> 11;
                    int sblk0 = (m0 & (SEQ - 1)) >> 4;
                    int h0 = n0 >> 6;
#pragma unroll
                    for (int j = 0; j < 8; ++j) {
                        int c = w * 8 + j;          // hloc(1b) | sblkl(3b) | ks2(1b)
                        int hloc = c >> 4, sblkl = (c >> 1) & 7, ks2 = c & 1;
                        // permuted local key row for fragment row lm of tile (g,t):
                        int keyrow = (sblkl >> 1) * 32 + ((lm >> 2) * 8) + ((sblkl & 1) * 4) + (lm & 3);
                        uint4 v4 = *(const uint4*)&t[keyrow * 136 + hloc * 64 + ks2 * 32 + quad * 8];
                        size_t chunk = ((size_t)(bb * NH + h0 + hloc) * 128 + sblk0 + sblkl) * 2 + ks2;
                        *(uint4*)&kout[chunk * 512 + lane * 8] = v4;
                    }
                }
            }
        } else {
            if constexpr (MREP == 4) {
                // V: PV A-fragment chunks. Chunk = ((b*NH+h)*128 + sblk)*4 + dblk,
                // 256 halves; element lane*4+j = V[d=dblk*16+lm][key=sblk*16+quad*4+j].
#pragma unroll
                for (int mt = 0; mt < MREP; ++mt) {
                    int row = m0 + wr * 64 + mt * 16;    // + quad*4+r in lane
                    int b = row >> 11;
                    int sblk = (row & (SEQ - 1)) >> 4;
#pragma unroll
                    for (int nt = 0; nt < 4; ++nt) {
                        int col = n0 + wc * 64 + nt * 16;  // + lm in lane
                        int h = col >> 6;
                        int dblk = (col & 63) >> 4;
                        size_t chunk = ((size_t)(b * NH + h) * 128 + sblk) * 4 + dblk;
                        uint2 pk;
                        pk.x = __builtin_bit_cast(u32, __builtin_amdgcn_cvt_pkrtz(acc[mt][nt][0], acc[mt][nt][1]));
                        pk.y = __builtin_bit_cast(u32, __builtin_amdgcn_cvt_pkrtz(acc[mt][nt][2], acc[mt][nt][3]));
                        *(uint2*)&vtout[chunk * 256 + lane * 4] = pk;
                    }
                }
            }
        }
    }
}

// ---------------- causal flash attention, split-k, K=32 f16 PV ----------------------
// Work items per bh (21): singles qt=0..10, qt=11..15 split into two k-range halves
// (flash split-k: no running max -> partials simply add). Grid 672, balance-ordered.
// Block: 4 waves x 32 q-rows; k-tile 128, double-buffered, ONE barrier per k-tile.
// K arrives with 32-key-group PERMUTED row order (see gemm_s z==1): the concat of the
// two 16-key tiles' packed exp pairs is exactly the K=32 f16 B-fragment (key=quad*8+j)
// -> PV uses mfma_f32_16x16x32_f16: 40 MFMA/iter instead of 80 (T: legacy K=16 shape
// wastes issue slots). V chunks unchanged: the 8 keys per lane are two contiguous
// halfx4 reads. Causal mask uses the permuted key index. T5: setprio(1) around MFMA
// clusters (attn regime: 2 desynced blocks/CU, measured +4-7%).
// Row-sum rides the matrix pipe via a ones-fragment MFMA (o5).
// itab entry: qt | k0<<4 | k1<<8 | split<<13 | part<<14
static __device__ const u16 itab[21] = {
    0x0B0A,                                  // s10 (11 iters)
    0x0A09,                                  // s9  (10)
    0x0908,                                  // s8  (9)
    0x280F, 0x708F, 0x6F7E, 0x0807,          // 15p0,15p1,14p1,s7 (8)
    0x270E, 0x270D, 0x6E7D, 0x6D6C, 0x0706,  // 14p0,13p0,13p1,12p1,s6 (7)
    0x260C, 0x260B, 0x6C6B, 0x0605,          // 12p0,11p0,11p1,s5 (6)
    0x0504, 0x0403, 0x0302, 0x0201, 0x0100   // s4..s0
};

__global__ __launch_bounds__(256, 2) void attn_kernel(const u16* __restrict__ Q,
                                                      const u16* __restrict__ Kf,
                                                      const _Float16* __restrict__ Vf,
                                                      u16* __restrict__ AO,
                                                      _Float16* __restrict__ Opart,
                                                      float* __restrict__ Lpart) {
    const int u  = blockIdx.x;
    const int e  = itab[u >> 5];
    const int bh = u & 31;
    const int qt = e & 15;
    const int k0 = (e >> 4) & 15;
    const int k1 = (e >> 8) & 31;
    const bool split = (e >> 13) & 1;
    const int part = e >> 14;
    const int b  = bh >> 4, h = bh & 15;
    const int q0 = qt * 128;
    const int tid = threadIdx.x, w = tid >> 6, lane = tid & 63;
    const int lm = lane & 15, quad = lane >> 4;

    __shared__ __align__(16) u16      lsK[2][16 * 512];   // 2 x 16KB: 16 K-frag chunks
    __shared__ __align__(16) _Float16 lsV[2][32 * 256];   // 2 x 16KB: 32 V-frag chunks

    bf16x8 qb[2][2];              // [qi][ks]; wave w owns q-rows w*32 .. w*32+31
#pragma unroll
    for (int qi = 0; qi < 2; ++qi)
#pragma unroll
        for (int ks = 0; ks < 2; ++ks)
            qb[qi][ks] = *(const bf16x8*)
                &Q[(size_t)(b * SEQ + q0 + w * 32 + qi * 16 + lm) * DM + h * DH + ks * 32 + quad * 8];

    const floatx4 z4 = {0.f, 0.f, 0.f, 0.f};
    floatx4 o[2][4];              // O^T[d][q]: d = dt*16+quad*4+r, q = lm
    floatx4 o5[2];                // row-sum accumulator (ones-row MFMA)
#pragma unroll
    for (int qi = 0; qi < 2; ++qi) {
#pragma unroll
        for (int dt = 0; dt < 4; ++dt) o[qi][dt] = z4;
        o5[qi] = z4;
    }

    // pre-fragmented K: 256 chunks/bh (1KB each); k-tile kt = chunks [kt*16, +16)
    const u16*      Kb = Kf + (size_t)bh * (256 * 512);
    // pre-fragmented V: 512 chunks/bh (512B each); k-tile kt = chunks [kt*32, +32)
    const _Float16* Vb = Vf + (size_t)bh * (128 * 4 * 256);

    auto stageKV = [&](int buf, int kt) {
#pragma unroll
        for (int j = 0; j < 4; ++j) {
            // K: 16KB linear (wave w copies chunks w*4..w*4+3)
            int kc = w * 4 + j;
            async16(Kb + ((size_t)kt * 16 + kc) * 512 + lane * 8,
                    &lsK[buf][kc * 512 + lane * 8]);
            // V: 16KB linear (wave w copies quarter w, 1KB per async16)
            int off = w * 2048 + j * 512 + lane * 8;
            async16(Vb + (size_t)kt * 8192 + off, &lsV[buf][off]);
        }
    };

    stageKV(k0 & 1, k0);
    const halfx8 ones8 = {(_Float16)1.f, (_Float16)1.f, (_Float16)1.f, (_Float16)1.f,
                          (_Float16)1.f, (_Float16)1.f, (_Float16)1.f, (_Float16)1.f};

    for (int kt = k0; kt < k1; ++kt) {
        __syncthreads();
        if (kt + 1 < k1) stageKV((kt + 1) & 1, kt + 1);
        const u16*      Lk = lsK[kt & 1];
        const _Float16* Lv = lsV[kt & 1];

        // QK^T: fragment-linear ka, each read feeds both q-fragments
        floatx4 s4[2][8];
#pragma unroll
        for (int qi = 0; qi < 2; ++qi)
#pragma unroll
            for (int st = 0; st < 8; ++st) s4[qi][st] = z4;
        __builtin_amdgcn_s_setprio(1);
#pragma unroll
        for (int ks = 0; ks < 2; ++ks)
#pragma unroll
            for (int st = 0; st < 8; ++st) {
                bf16x8 ka = *(const bf16x8*)&Lk[(st * 2 + ks) * 512 + lane * 8];
#pragma unroll
                for (int qi = 0; qi < 2; ++qi)
                    s4[qi][st] = __builtin_amdgcn_mfma_f32_16x16x32_bf16(ka, qb[qi][ks], s4[qi][st], 0, 0, 0);
            }
        __builtin_amdgcn_s_setprio(0);

        const bool diag = (kt == qt);
#pragma unroll
        for (int g = 0; g < 4; ++g) {
            halfx8 pb8[2];
#pragma unroll
            for (int qi = 0; qi < 2; ++qi) {
#pragma unroll
                for (int t = 0; t < 2; ++t) {
                    int st = g * 2 + t;
#pragma unroll
                    for (int r = 0; r < 4; ++r) {
                        float v = s4[qi][st][r];
                        if (diag) {
                            // permuted key index (matches gemm_s z==1 layout)
                            int keyloc = g * 32 + quad * 8 + t * 4 + r;
                            if (keyloc > w * 32 + qi * 16 + lm) v = -1e30f;
                        }
                        s4[qi][st][r] = __builtin_amdgcn_exp2f(v);   // raw v_exp_f32
                    }
                }
                uint4 pk4;
                pk4.x = __builtin_bit_cast(u32, __builtin_amdgcn_cvt_pkrtz(s4[qi][g * 2][0],     s4[qi][g * 2][1]));
                pk4.y = __builtin_bit_cast(u32, __builtin_amdgcn_cvt_pkrtz(s4[qi][g * 2][2],     s4[qi][g * 2][3]));
                pk4.z = __builtin_bit_cast(u32, __builtin_amdgcn_cvt_pkrtz(s4[qi][g * 2 + 1][0], s4[qi][g * 2 + 1][1]));
                pk4.w = __builtin_bit_cast(u32, __builtin_amdgcn_cvt_pkrtz(s4[qi][g * 2 + 1][2], s4[qi][g * 2 + 1][3]));
                pb8[qi] = __builtin_bit_cast(halfx8, pk4);
            }
            // PV: K=32 f16 MFMA; va8 = two contiguous halfx4 from the 16-key V chunks:
            // key quad*8+j -> chunk (2g + (quad>>1), dt), halves (quad&1)*128+lm*4 (+64)
            __builtin_amdgcn_s_setprio(1);
#pragma unroll
            for (int dt = 0; dt < 4; ++dt) {
                const _Float16* cb = &Lv[(((2 * g + (quad >> 1)) * 4 + dt) * 256) + (quad & 1) * 128 + lm * 4];
                halfx4 lo = *(const halfx4*)cb;
                halfx4 hi = *(const halfx4*)(cb + 64);
                halfx8 va8 = __builtin_shufflevector(lo, hi, 0, 1, 2, 3, 4, 5, 6, 7);
#pragma unroll
                for (int qi = 0; qi < 2; ++qi)
                    o[qi][dt] = __builtin_amdgcn_mfma_f32_16x16x32_f16(va8, pb8[qi], o[qi][dt], 0, 0, 0);
            }
#pragma unroll
            for (int qi = 0; qi < 2; ++qi)
                o5[qi] = __builtin_amdgcn_mfma_f32_16x16x32_f16(ones8, pb8[qi], o5[qi], 0, 0, 0);
            __builtin_amdgcn_s_setprio(0);
        }
    }

    if (split) {
        // unnormalized O^T partial (f16, |o| <~ 1e4 << 65504) + lsum partial
        const int pi = (bh * 5 + (qt - 11)) * 2 + part;
        _Float16* Od = Opart + (size_t)pi * (128 * 64);
#pragma unroll
        for (int qi = 0; qi < 2; ++qi) {
            const int q = w * 32 + qi * 16 + lm;
#pragma unroll
            for (int dt = 0; dt < 4; ++dt) {
                uintx2 pk2;
                pk2.x = __builtin_bit_cast(u32, __builtin_amdgcn_cvt_pkrtz(o[qi][dt][0], o[qi][dt][1]));
                pk2.y = __builtin_bit_cast(u32, __builtin_amdgcn_cvt_pkrtz(o[qi][dt][2], o[qi][dt][3]));
                *(uintx2*)&Od[(size_t)q * 64 + dt * 16 + quad * 4] = pk2;
            }
            if (quad == 0) Lpart[pi * 128 + q] = o5[qi][0];
        }
        return;
    }

    // o5[qi] rows all hold the full row-sum for q = lm (ones-row MFMA sums all keys)
    float rl[2] = {1.0f / o5[0][0], 1.0f / o5[1][0]};

    // epilogue: O^T (reg) -> LDS (swizzled natural [q][d]) -> shuffled-frag AO store
    __syncthreads();                       // all waves done with lsK/lsV
    u16* eb = (u16*)&lsK[0][0];            // 128x64 bf16 = 16 KB (= lsK buffer 0)
#pragma unroll
    for (int qi = 0; qi < 2; ++qi) {
        const int q = w * 32 + qi * 16 + lm;
#pragma unroll
        for (int dt = 0; dt < 4; ++dt) {
            uint2 pk;
            pk.x = (u32)f2bf(o[qi][dt][0] * rl[qi]) | ((u32)f2bf(o[qi][dt][1] * rl[qi]) << 16);
            pk.y = (u32)f2bf(o[qi][dt][2] * rl[qi]) | ((u32)f2bf(o[qi][dt][3] * rl[qi]) << 16);
            int ch = (dt * 2 + (quad >> 1)) ^ (lm & 7);
            *(uint2*)&eb[q * 64 + ch * 8 + (quad & 1) * 4] = pk;
        }
    }
    __syncthreads();
    const size_t rowblk0 = (size_t)((b * SEQ + q0) >> 4);
#pragma unroll
    for (int rbi = 0; rbi < 2; ++rbi) {
#pragma unroll
        for (int kt = 0; kt < 2; ++kt) {
            uint4 v = *(const uint4*)&eb[((w * 2 + rbi) * 16 + lm) * 64 + ((kt * 4 + quad) ^ (lm & 7)) * 8];
            *(uint4*)&AO[((rowblk0 + w * 2 + rbi) * 32 + (h * 2 + kt)) * 512 + lane * 8] = v;
        }
    }
}

// ---------------- split-k combine: O = (O0+O1)/(l0+l1) -> shuffled-frag AO ----------
// 160 blocks (32 bh x 5 split q-tiles), 256 threads; ~8MB traffic.
__global__ __launch_bounds__(256) void combine_kernel(const _Float16* __restrict__ Op,
                                                      const float* __restrict__ Lp,
                                                      u16* __restrict__ AO) {
    const int g = blockIdx.x;              // bh*5 + (qt-11)
    const int bh = g / 5, qto = g - bh * 5;
    const int qt = 11 + qto;
    const int b = bh >> 4, h = bh & 15;
    const int q0 = qt * 128;
    const int pi0 = g * 2;
    const _Float16* O0 = Op + (size_t)pi0 * (128 * 64);
    const _Float16* O1 = O0 + 128 * 64;
    const float* L0 = Lp + pi0 * 128;
    const float* L1 = L0 + 128;
    const int tid = threadIdx.x;
#pragma unroll
    for (int rep = 0; rep < 4; ++rep) {
        int idx = rep * 256 + tid;         // 16 chunks x 64 lanes
        int chunk = idx >> 6, lane = idx & 63;
        int rb = chunk >> 1, kt2 = chunk & 1;
        int lm = lane & 15, quad = lane >> 4;
        int q = rb * 16 + lm;
        int d = kt2 * 32 + quad * 8;
        float rl = 1.0f / (L0[q] + L1[q]);
        halfx8 a = *(const halfx8*)&O0[(size_t)q * 64 + d];
        halfx8 c = *(const halfx8*)&O1[(size_t)q * 64 + d];
        uint4 v;
        u32 pk[4];
#pragma unroll
        for (int j = 0; j < 4; ++j) {
            float v0 = ((float)a[2 * j]     + (float)c[2 * j])     * rl;
            float v1 = ((float)a[2 * j + 1] + (float)c[2 * j + 1]) * rl;
            pk[j] = (u32)f2bf(v0) | ((u32)f2bf(v1) << 16);
        }
        v.x = pk[0]; v.y = pk[1]; v.z = pk[2]; v.w = pk[3];
        size_t rowblk = ((size_t)(b * SEQ + q0) >> 4) + rb;
        *(uint4*)&AO[(rowblk * 32 + (h * 2 + kt2)) * 512 + lane * 8] = v;
    }
}

extern "C" void kernel_launch(void* const* d_in, const int* in_sizes, int n_in,
                              void* d_out, int out_size, void* d_ws, size_t ws_size,
                              hipStream_t stream) {
    const float* x   = (const float*)d_in[0];
    const int*   pos = (const int*)d_in[1];
    float* out = (float*)d_out;

    u16* ws = (u16*)d_ws;
    const size_t MD = (size_t)MM * DM;
    const size_t DD = (size_t)DM * DM;
    u16* Xsh = ws;                        // shuffled X; dead after QKV -> reused as AOsh
    u16* Wsh = ws + MD;                   // 4 shuffled weights (q,k,v,o)
    u16* Qbf = ws + MD + 4 * DD;          // Q natural bf16
    u16* Kfb = Qbf + MD;                  // K as QK-A-fragment chunks (permuted key order)
    u16* VtB = Kfb + MD;                  // f16 V as PV-A-fragment chunks
    float2* ropetab = (float2*)(VtB + MD);
    _Float16* Vt = (_Float16*)VtB;
    u16* AOsh = Xsh;
    // split-k partials: O f16 overlays the DEAD Wq/Wk/Wv region (5.24MB <= 6MB);
    // lsum f32 after the RoPE table (+160KB)
    _Float16* Opart = (_Float16*)Wsh;
    float* Lpart = (float*)(ropetab + SEQ * 32);

    // prep: bf16 shuffled X + 4 W, RoPE table (one launch)
    prep_kernel<<<dim3(128, 16), 256, 0, stream>>>(
        x, (const float*)d_in[2], (const float*)d_in[3], (const float*)d_in[4],
        (const float*)d_in[5], Xsh, Wsh, pos, ropetab);

    // Q/K/V projections, per-z blocks (z = blockIdx.z), 128x128 tiles, 3 blocks/CU;
    // counted-vmcnt triple-buffer K-loop; RoPE fused on Q,K; K/V written pre-fragmented
    gemm_s<4, false><<<dim3(32, 8, 3), 256, 0, stream>>>(
        Xsh, Wsh, Qbf, nullptr, Vt, Kfb, ropetab);

    // causal flash attention, split-k (672 balanced items; splits write partials)
    attn_kernel<<<dim3(672), 256, 0, stream>>>(Qbf, Kfb, Vt, AOsh, Opart, Lpart);

    // combine split-k partials into AO
    combine_kernel<<<dim3(160), 256, 0, stream>>>(Opart, Lpart, AOsh);

    // output projection -> fp32 d_out (64x128 tiles, 2 blocks/CU)
    gemm_s<2, true><<<dim3(64, 8, 1), 256, 0, stream>>>(
        AOsh, Wsh + 3 * DD, nullptr, out, nullptr, nullptr, ropetab);
}

// Round 10
// 174.158 us; speedup vs baseline: 1.0372x; 1.0372x over previous
//
#include <hip/hip_runtime.h>
#include <math.h>

typedef unsigned short u16;
typedef unsigned int   u32;
typedef __attribute__((ext_vector_type(8))) short bf16x8;
typedef __attribute__((ext_vector_type(4))) float floatx4;
typedef __attribute__((ext_vector_type(4))) _Float16 halfx4;
typedef __attribute__((ext_vector_type(8))) _Float16 halfx8;
typedef __attribute__((ext_vector_type(2))) unsigned int uintx2;

// B=2, S=2048, D=1024, H=16, Dh=64, M=B*S=4096
#define SEQ 2048
#define DM  1024
#define NH  16
#define DH  64
#define MM  4096
#define QSCALE 0.18033688011112042f   // 0.125 * log2(e), folded into Q

__device__ __forceinline__ u16 f2bf(float f) {
    u32 u = __builtin_bit_cast(u32, f);
    u += 0x7fffu + ((u >> 16) & 1u);
    return (u16)(u >> 16);
}

__device__ __forceinline__ void async16(const void* g, void* l) {
    __builtin_amdgcn_global_load_lds(
        (const __attribute__((address_space(1))) void*)g,
        (__attribute__((address_space(3))) void*)l, 16, 0, 0);
}

// ---------------- prep: fp32 -> bf16 shuffled layout + RoPE table -------------------
// Shuffled layout: tile (rowblk=row/16, ktile=col/32); element [m=lm][k=quad*8+j]
// stored flat at (rowblk*32 + ktile)*512 + lane*8 + j. One dwordx4/lane per fragment.
// First 256 linear blocks additionally fill the RoPE table (2048x32 float2).
__global__ __launch_bounds__(256) void prep_kernel(const float* __restrict__ x,
                                                   const float* __restrict__ w0,
                                                   const float* __restrict__ w1,
                                                   const float* __restrict__ w2,
                                                   const float* __restrict__ w3,
                                                   u16* __restrict__ Xsh,
                                                   u16* __restrict__ Wsh,
                                                   const int* __restrict__ pos,
                                                   float2* __restrict__ tab) {
    const int bid = blockIdx.x, cb = blockIdx.y, tid = threadIdx.x;

    // RoPE table side-job
    int lin = bid * 16 + cb;
    if (lin < 256) {
        int i = lin * 256 + tid;       // 65536 = 2048*32
        int p = i >> 5, d2 = i & 31;
        float freq = __expf(-(float)d2 * (9.2103403719761836f / 32.0f));
        float sv, cv;
        sincosf((float)pos[p] * freq, &sv, &cv);
        tab[i] = make_float2(cv, sv);
    }

    const float* src; u16* dst; int row0;
    if (bid < 64) { src = x; dst = Xsh; row0 = bid * 64; }
    else {
        int wi = (bid - 64) >> 4;
        src = (wi == 0) ? w0 : (wi == 1) ? w1 : (wi == 2) ? w2 : w3;
        dst = Wsh + (size_t)wi * DM * DM;
        row0 = ((bid - 64) & 15) * 64;
    }
    __shared__ __align__(16) u16 t[64 * 64];   // 8-elem chunks XOR-swizzled by row&7
#pragma unroll
    for (int rep = 0; rep < 4; ++rep) {
        int f = rep * 256 + tid;
        int r = f >> 4, c4 = f & 15;
        float4 v = *(const float4*)&src[(size_t)(row0 + r) * DM + cb * 64 + c4 * 4];
        uint2 pk;
        pk.x = (u32)f2bf(v.x) | ((u32)f2bf(v.y) << 16);
        pk.y = (u32)f2bf(v.z) | ((u32)f2bf(v.w) << 16);
        int ch = (c4 >> 1) ^ (r & 7);
        *(uint2*)&t[r * 64 + ch * 8 + (c4 & 1) * 4] = pk;
    }
    __syncthreads();
#pragma unroll
    for (int rep = 0; rep < 2; ++rep) {
        int s = rep * 256 + tid;
        int tile = s >> 6, l = s & 63;
        int mt = tile >> 1, kt = tile & 1, lm = l & 15, quad = l >> 4;
        int m = mt * 16 + lm;
        uint4 v = *(const uint4*)&t[m * 64 + ((kt * 4 + quad) ^ (m & 7)) * 8];
        size_t rowblk = (size_t)(row0 >> 4) + mt;
        size_t ktile  = cb * 2 + kt;
        *(uint4*)&dst[(rowblk * 32 + ktile) * 512 + l * 8] = v;
    }
}

// ---------------- per-z NT GEMM, counted-vmcnt triple-buffer K-loop (T4) ------------
// C_z[M,1024] = A * W_z^T, z = blockIdx.z. Block tile BM x 128 (BM = MREP*32),
// 4 waves (2x2), wave tile (MREP*16) x 64. BK=32, 32 K-steps.
// THREE LDS buffers; per iter: {s_waitcnt vmcnt(LPS); s_barrier} (single asm, memory
// clobber) -> waits ONLY for tile it (tile it+1 stays in flight across the barrier),
// then issue stage(it+2), then MFMA. T4: never vmcnt(0) in the main loop.
// Epilogues: z==0 Q (RoPE+QSCALE, natural bf16); z==1 K (RoPE + LDS-bounce
// transpose -> QK-A-fragment chunks); z==2 V (PV-A-fragment chunks);
// OUTF32 (Wo, MREP=2) writes fp32.
template<int MREP, bool OUTF32>
__global__ __launch_bounds__(256, (MREP == 4) ? 3 : 2)
void gemm_s(const u16* __restrict__ Ash,
            const u16* __restrict__ Wbase,
            u16* __restrict__ qout,
            float* __restrict__ outf,
            _Float16* __restrict__ vtout,
            u16* __restrict__ kout,
            const float2* __restrict__ ropetab) {
    constexpr int BM  = MREP * 32;         // 128 (QKV) or 64 (Wo)
    constexpr int AC  = 2 * MREP;          // A chunks per K-step
    constexpr int APW = AC / 4;            // A chunks staged per wave
    constexpr int STEP = (AC + 8) * 512;   // u16 per LDS buffer
    constexpr int SHN  = 3 * STEP;         // 48KB (QKV; covers 17408-u16 K-scratch) / 36KB (Wo)

    const int z  = blockIdx.z;
    const u16* Wp = Wbase + (size_t)z * (DM * DM);
    const int m0 = blockIdx.x * BM, n0 = blockIdx.y * 128;
    const int tid = threadIdx.x, lane = tid & 63, w = tid >> 6;
    const int wr = w >> 1, wc = w & 1;
    const int lm = lane & 15, quad = lane >> 4;
    const int rb0 = m0 >> 4, cb0 = n0 >> 4;

    __shared__ __align__(16) u16 sh[SHN];

    auto stage = [&](int buf, int it) {
        u16* la = sh + buf * STEP;
        u16* lb = la + AC * 512;
#pragma unroll
        for (int j = 0; j < APW; ++j) {
            int c = w * APW + j;
            async16(Ash + ((size_t)(rb0 + c) * 32 + it) * 512 + lane * 8,
                    &la[c * 512 + lane * 8]);
        }
#pragma unroll
        for (int j = 0; j < 2; ++j) {
            int c = w * 2 + j;
            async16(Wp + ((size_t)(cb0 + c) * 32 + it) * 512 + lane * 8,
                    &lb[c * 512 + lane * 8]);
        }
    };

    floatx4 acc[MREP][4];
    const floatx4 z4 = {0.f, 0.f, 0.f, 0.f};
#pragma unroll
    for (int mt = 0; mt < MREP; ++mt)
#pragma unroll
        for (int nt = 0; nt < 4; ++nt) acc[mt][nt] = z4;

    stage(0, 0);
    stage(1, 1);

    int cur = 0;
    for (int it = 0; it < 32; ++it) {
        // counted wait: tile it landed; tile it+1's loads stay in flight (LPS=APW+2).
        if (it == 31) {
            asm volatile("s_waitcnt vmcnt(0)\n\ts_barrier" ::: "memory");
        } else {
            if constexpr (MREP == 4)
                asm volatile("s_waitcnt vmcnt(4)\n\ts_barrier" ::: "memory");
            else
                asm volatile("s_waitcnt vmcnt(3)\n\ts_barrier" ::: "memory");
        }
        if (it < 30) {
            int pre = cur - 1; if (pre < 0) pre = 2;   // (it+2) % 3
            stage(pre, it + 2);
        }
        const u16* la = sh + cur * STEP;
        const u16* lb = la + AC * 512;
        bf16x8 a[MREP], b[4];
#pragma unroll
        for (int mt = 0; mt < MREP; ++mt)
            a[mt] = *(const bf16x8*)&la[(wr * MREP + mt) * 512 + lane * 8];
#pragma unroll
        for (int nt = 0; nt < 4; ++nt)
            b[nt] = *(const bf16x8*)&lb[(wc * 4 + nt) * 512 + lane * 8];
#pragma unroll
        for (int mt = 0; mt < MREP; ++mt)
#pragma unroll
            for (int nt = 0; nt < 4; ++nt)
                acc[mt][nt] = __builtin_amdgcn_mfma_f32_16x16x32_bf16(
                    a[mt], b[nt], acc[mt][nt], 0, 0, 0);
        ++cur; if (cur == 3) cur = 0;
    }
    __syncthreads();   // all waves done with sh before epilogue reuse (z==1 scratch)

    if constexpr (OUTF32) {
#pragma unroll
        for (int mt = 0; mt < MREP; ++mt)
#pragma unroll
            for (int r = 0; r < 4; ++r) {
                int row = m0 + wr * (MREP * 16) + mt * 16 + quad * 4 + r;
#pragma unroll
                for (int nt = 0; nt < 4; ++nt) {
                    int col = n0 + wc * 64 + nt * 16 + lm;
                    outf[(size_t)row * DM + col] = acc[mt][nt][r];
                }
            }
        return;
    } else {
        if (z == 0) {
            // Q: RoPE + QSCALE, natural bf16 (pair store via lane-parity)
#pragma unroll
            for (int mt = 0; mt < MREP; ++mt)
#pragma unroll
                for (int r = 0; r < 4; ++r) {
                    int row = m0 + wr * (MREP * 16) + mt * 16 + quad * 4 + r;
#pragma unroll
                    for (int nt = 0; nt < 4; ++nt) {
                        int col = n0 + wc * 64 + nt * 16 + lm;
                        float v  = acc[mt][nt][r];
                        float pv = __shfl_xor(v, 1);
                        float2 cs = ropetab[(row & (SEQ - 1)) * 32 + ((col & 63) >> 1)];
                        v = (lm & 1) ? fmaf(pv, cs.y, v * cs.x) : fmaf(v, cs.x, -pv * cs.y);
                        v *= QSCALE;
                        float hv = __shfl_xor(v, 1);
                        if (!(lm & 1)) {
                            u32 pk = (u32)f2bf(v) | ((u32)f2bf(hv) << 16);
                            *(u32*)&qout[(size_t)row * DM + col] = pk;
                        }
                    }
                }
        } else if (z == 1) {
            if constexpr (MREP == 4) {
                // K: RoPE, LDS-bounce transpose into QK A-fragment chunks.
                // Chunk = ((bh*128 + sblk)*2 + ks2), 512 bf16;
                // element lane*8+j = K[key=sblk*16+lm][kd=ks2*32+quad*8+j].
                u16* t = sh;   // 128 x 136 u16 scratch (union over stage buffers)
#pragma unroll
                for (int mt = 0; mt < MREP; ++mt)
#pragma unroll
                    for (int r = 0; r < 4; ++r) {
                        int rl  = wr * 64 + mt * 16 + quad * 4 + r;
                        int row = m0 + rl;
#pragma unroll
                        for (int nt = 0; nt < 4; ++nt) {
                            int cl  = wc * 64 + nt * 16 + lm;
                            int col = n0 + cl;
                            float v  = acc[mt][nt][r];
                            float pv = __shfl_xor(v, 1);
                            float2 cs = ropetab[(row & (SEQ - 1)) * 32 + ((col & 63) >> 1)];
                            v = (lm & 1) ? fmaf(pv, cs.y, v * cs.x) : fmaf(v, cs.x, -pv * cs.y);
                            t[rl * 136 + cl] = f2bf(v);
                        }
                    }
                __syncthreads();
                {
                    int bb = m0 >> 11;
                    int sblk0 = (m0 & (SEQ - 1)) >> 4;
                    int h0 = n0 >> 6;
#pragma unroll
                    for (int j = 0; j < 8; ++j) {
                        int c = w * 8 + j;          // hloc(1b) | sblkl(3b) | ks2(1b)
                        int hloc = c >> 4, sblkl = (c >> 1) & 7, ks2 = c & 1;
                        uint4 v4 = *(const uint4*)&t[(sblkl * 16 + lm) * 136 + hloc * 64 + ks2 * 32 + quad * 8];
                        size_t chunk = ((size_t)(bb * NH + h0 + hloc) * 128 + sblk0 + sblkl) * 2 + ks2;
                        *(uint4*)&kout[chunk * 512 + lane * 8] = v4;
                    }
                }
            }
        } else {
            if constexpr (MREP == 4) {
                // V: PV A-fragment chunks. Chunk = ((b*NH+h)*128 + sblk)*4 + dblk,
                // 256 halves; element lane*4+j = V[d=dblk*16+lm][key=sblk*16+quad*4+j].
#pragma unroll
                for (int mt = 0; mt < MREP; ++mt) {
                    int row = m0 + wr * 64 + mt * 16;    // + quad*4+r in lane
                    int b = row >> 11;
                    int sblk = (row & (SEQ - 1)) >> 4;
#pragma unroll
                    for (int nt = 0; nt < 4; ++nt) {
                        int col = n0 + wc * 64 + nt * 16;  // + lm in lane
                        int h = col >> 6;
                        int dblk = (col & 63) >> 4;
                        size_t chunk = ((size_t)(b * NH + h) * 128 + sblk) * 4 + dblk;
                        uint2 pk;
                        pk.x = __builtin_bit_cast(u32, __builtin_amdgcn_cvt_pkrtz(acc[mt][nt][0], acc[mt][nt][1]));
                        pk.y = __builtin_bit_cast(u32, __builtin_amdgcn_cvt_pkrtz(acc[mt][nt][2], acc[mt][nt][3]));
                        *(uint2*)&vtout[chunk * 256 + lane * 4] = pk;
                    }
                }
            }
        }
    }
}

// ---------------- causal flash attention, split-k, fragment-linear LDS --------------
// Work items per bh (24): singles qt=0..7 (full k-range), and qt=8..15 split into
// two k-range halves (flash split-k: no running max -> partials simply add).
// Max item = 8 iters (round-8's 11-iter s10 was the makespan tail; 4352 total iters /
// 512 block slots = 8.5 avg, so all-items<=8 evens the schedule). Grid 768,
// balance-ordered descending. Block: 4 waves x 32 q-rows; k-tile 128, double-buffered,
// ONE barrier per k-tile. ALL LDS accesses fragment-linear (chunk + lane*16B/8B):
// zero bank conflicts, zero per-read address VALU. K/V arrive PRE-FRAGMENTED from the
// QKV GEMM (linear coalesced staging). exp2 via __builtin_amdgcn_exp2f (raw
// v_exp_f32). Row-sum rides the matrix pipe via a ones-fragment MFMA (o5).
// Singles write AO (shuffled-frag); splits write unnormalized O-partial f16 + lsum
// into dedicated workspace (no overlay: ws is ~268MB per the fill counters).
// itab entry: qt | k0<<4 | k1<<8 | split<<13 | part<<14
static __device__ const u16 itab[24] = {
    0x280F, 0x708F, 0x280E, 0x0807,          // 8 iters: 15p0,15p1,14p0,s7
    0x6F8E, 0x270D, 0x6E7D, 0x270C, 0x0706,  // 7 iters: 14p1,13p0,13p1,12p0,s6
    0x6D7C, 0x260B, 0x6C6B, 0x260A, 0x0605,  // 6 iters: 12p1,11p0,11p1,10p0,s5
    0x6B6A, 0x2509, 0x6A59, 0x2508, 0x0504,  // 5 iters: 10p1,9p0,9p1,8p0,s4
    0x6958, 0x0403,                          // 4 iters: 8p1,s3
    0x0302, 0x0201, 0x0100                   // s2,s1,s0
};

__global__ __launch_bounds__(256, 2) void attn_kernel(const u16* __restrict__ Q,
                                                      const u16* __restrict__ Kf,
                                                      const _Float16* __restrict__ Vf,
                                                      u16* __restrict__ AO,
                                                      _Float16* __restrict__ Opart,
                                                      float* __restrict__ Lpart) {
    const int u  = blockIdx.x;
    const int e  = itab[u >> 5];
    const int bh = u & 31;
    const int qt = e & 15;
    const int k0 = (e >> 4) & 15;
    const int k1 = (e >> 8) & 31;
    const bool split = (e >> 13) & 1;
    const int part = e >> 14;
    const int b  = bh >> 4, h = bh & 15;
    const int q0 = qt * 128;
    const int tid = threadIdx.x, w = tid >> 6, lane = tid & 63;
    const int lm = lane & 15, quad = lane >> 4;

    __shared__ __align__(16) u16      lsK[2][16 * 512];   // 2 x 16KB: 16 K-frag chunks
    __shared__ __align__(16) _Float16 lsV[2][32 * 256];   // 2 x 16KB: 32 V-frag chunks

    bf16x8 qb[2][2];              // [qi][ks]; wave w owns q-rows w*32 .. w*32+31
#pragma unroll
    for (int qi = 0; qi < 2; ++qi)
#pragma unroll
        for (int ks = 0; ks < 2; ++ks)
            qb[qi][ks] = *(const bf16x8*)
                &Q[(size_t)(b * SEQ + q0 + w * 32 + qi * 16 + lm) * DM + h * DH + ks * 32 + quad * 8];

    const floatx4 z4 = {0.f, 0.f, 0.f, 0.f};
    floatx4 o[2][4];              // O^T[d][q]: d = dt*16+quad*4+r, q = lm
    floatx4 o5[2];                // row-sum accumulator (ones-row MFMA)
#pragma unroll
    for (int qi = 0; qi < 2; ++qi) {
#pragma unroll
        for (int dt = 0; dt < 4; ++dt) o[qi][dt] = z4;
        o5[qi] = z4;
    }

    // pre-fragmented K: 256 chunks/bh (1KB each); k-tile kt = chunks [kt*16, +16)
    const u16*      Kb = Kf + (size_t)bh * (256 * 512);
    // pre-fragmented V: 512 chunks/bh (512B each); k-tile kt = chunks [kt*32, +32)
    const _Float16* Vb = Vf + (size_t)bh * (128 * 4 * 256);

    auto stageKV = [&](int buf, int kt) {
#pragma unroll
        for (int j = 0; j < 4; ++j) {
            // K: 16KB linear (wave w copies chunks w*4..w*4+3)
            int kc = w * 4 + j;
            async16(Kb + ((size_t)kt * 16 + kc) * 512 + lane * 8,
                    &lsK[buf][kc * 512 + lane * 8]);
            // V: 16KB linear (wave w copies quarter w, 1KB per async16)
            int off = w * 2048 + j * 512 + lane * 8;
            async16(Vb + (size_t)kt * 8192 + off, &lsV[buf][off]);
        }
    };

    stageKV(k0 & 1, k0);
    const halfx4 ones = {(_Float16)1.f, (_Float16)1.f, (_Float16)1.f, (_Float16)1.f};

    for (int kt = k0; kt < k1; ++kt) {
        __syncthreads();
        if (kt + 1 < k1) stageKV((kt + 1) & 1, kt + 1);
        const u16*      Lk = lsK[kt & 1];
        const _Float16* Lv = lsV[kt & 1];

        // QK^T: fragment-linear ka, each read feeds both q-fragments
        floatx4 s4[2][8];
#pragma unroll
        for (int qi = 0; qi < 2; ++qi)
#pragma unroll
            for (int st = 0; st < 8; ++st) s4[qi][st] = z4;
#pragma unroll
        for (int ks = 0; ks < 2; ++ks)
#pragma unroll
            for (int st = 0; st < 8; ++st) {
                bf16x8 ka = *(const bf16x8*)&Lk[(st * 2 + ks) * 512 + lane * 8];
#pragma unroll
                for (int qi = 0; qi < 2; ++qi)
                    s4[qi][st] = __builtin_amdgcn_mfma_f32_16x16x32_bf16(ka, qb[qi][ks], s4[qi][st], 0, 0, 0);
            }

        const bool diag = (kt == qt);
#pragma unroll
        for (int st = 0; st < 8; ++st) {
            halfx4 pb2[2];
#pragma unroll
            for (int qi = 0; qi < 2; ++qi) {
#pragma unroll
                for (int r = 0; r < 4; ++r) {
                    float v = s4[qi][st][r];
                    if (diag) {
                        int keyloc = st * 16 + quad * 4 + r;
                        if (keyloc > w * 32 + qi * 16 + lm) v = -1e30f;
                    }
                    s4[qi][st][r] = __builtin_amdgcn_exp2f(v);   // raw v_exp_f32
                }
                uintx2 pk2;
                pk2.x = __builtin_bit_cast(u32, __builtin_amdgcn_cvt_pkrtz(s4[qi][st][0], s4[qi][st][1]));
                pk2.y = __builtin_bit_cast(u32, __builtin_amdgcn_cvt_pkrtz(s4[qi][st][2], s4[qi][st][3]));
                pb2[qi] = __builtin_bit_cast(halfx4, pk2);
            }
            // PV: fragment-linear va, feeds both q-fragments; lsum via ones-MFMA
#pragma unroll
            for (int dt = 0; dt < 4; ++dt) {
                halfx4 va = *(const halfx4*)&Lv[(st * 4 + dt) * 256 + lane * 4];
#pragma unroll
                for (int qi = 0; qi < 2; ++qi)
                    o[qi][dt] = __builtin_amdgcn_mfma_f32_16x16x16f16(va, pb2[qi], o[qi][dt], 0, 0, 0);
            }
#pragma unroll
            for (int qi = 0; qi < 2; ++qi)
                o5[qi] = __builtin_amdgcn_mfma_f32_16x16x16f16(ones, pb2[qi], o5[qi], 0, 0, 0);
        }
    }

    if (split) {
        // unnormalized O^T partial (f16, |o| <~ 1e4 << 65504) + lsum partial
        const int pi = (bh * 8 + (qt - 8)) * 2 + part;
        _Float16* Od = Opart + (size_t)pi * (128 * 64);
#pragma unroll
        for (int qi = 0; qi < 2; ++qi) {
            const int q = w * 32 + qi * 16 + lm;
#pragma unroll
            for (int dt = 0; dt < 4; ++dt) {
                uintx2 pk2;
                pk2.x = __builtin_bit_cast(u32, __builtin_amdgcn_cvt_pkrtz(o[qi][dt][0], o[qi][dt][1]));
                pk2.y = __builtin_bit_cast(u32, __builtin_amdgcn_cvt_pkrtz(o[qi][dt][2], o[qi][dt][3]));
                *(uintx2*)&Od[(size_t)q * 64 + dt * 16 + quad * 4] = pk2;
            }
            if (quad == 0) Lpart[pi * 128 + q] = o5[qi][0];
        }
        return;
    }

    // o5[qi] rows all hold the full row-sum for q = lm (ones-row MFMA sums all keys)
    float rl[2] = {1.0f / o5[0][0], 1.0f / o5[1][0]};

    // epilogue: O^T (reg) -> LDS (swizzled natural [q][d]) -> shuffled-frag AO store
    __syncthreads();                       // all waves done with lsK/lsV
    u16* eb = (u16*)&lsK[0][0];            // 128x64 bf16 = 16 KB (= lsK buffer 0)
#pragma unroll
    for (int qi = 0; qi < 2; ++qi) {
        const int q = w * 32 + qi * 16 + lm;
#pragma unroll
        for (int dt = 0; dt < 4; ++dt) {
            uint2 pk;
            pk.x = (u32)f2bf(o[qi][dt][0] * rl[qi]) | ((u32)f2bf(o[qi][dt][1] * rl[qi]) << 16);
            pk.y = (u32)f2bf(o[qi][dt][2] * rl[qi]) | ((u32)f2bf(o[qi][dt][3] * rl[qi]) << 16);
            int ch = (dt * 2 + (quad >> 1)) ^ (lm & 7);
            *(uint2*)&eb[q * 64 + ch * 8 + (quad & 1) * 4] = pk;
        }
    }
    __syncthreads();
    const size_t rowblk0 = (size_t)((b * SEQ + q0) >> 4);
#pragma unroll
    for (int rbi = 0; rbi < 2; ++rbi) {
#pragma unroll
        for (int kt = 0; kt < 2; ++kt) {
            uint4 v = *(const uint4*)&eb[((w * 2 + rbi) * 16 + lm) * 64 + ((kt * 4 + quad) ^ (lm & 7)) * 8];
            *(uint4*)&AO[((rowblk0 + w * 2 + rbi) * 32 + (h * 2 + kt)) * 512 + lane * 8] = v;
        }
    }
}

// ---------------- split-k combine: O = (O0+O1)/(l0+l1) -> shuffled-frag AO ----------
// 256 blocks (32 bh x 8 split q-tiles), 256 threads; ~12MB traffic.
__global__ __launch_bounds__(256) void combine_kernel(const _Float16* __restrict__ Op,
                                                      const float* __restrict__ Lp,
                                                      u16* __restrict__ AO) {
    const int g = blockIdx.x;              // bh*8 + (qt-8)
    const int bh = g >> 3, qto = g & 7;
    const int qt = 8 + qto;
    const int b = bh >> 4, h = bh & 15;
    const int q0 = qt * 128;
    const int pi0 = g * 2;
    const _Float16* O0 = Op + (size_t)pi0 * (128 * 64);
    const _Float16* O1 = O0 + 128 * 64;
    const float* L0 = Lp + pi0 * 128;
    const float* L1 = L0 + 128;
    const int tid = threadIdx.x;
#pragma unroll
    for (int rep = 0; rep < 4; ++rep) {
        int idx = rep * 256 + tid;         // 16 chunks x 64 lanes
        int chunk = idx >> 6, lane = idx & 63;
        int rb = chunk >> 1, kt2 = chunk & 1;
        int lm = lane & 15, quad = lane >> 4;
        int q = rb * 16 + lm;
        int d = kt2 * 32 + quad * 8;
        float rl = 1.0f / (L0[q] + L1[q]);
        halfx8 a = *(const halfx8*)&O0[(size_t)q * 64 + d];
        halfx8 c = *(const halfx8*)&O1[(size_t)q * 64 + d];
        uint4 v;
        u32 pk[4];
#pragma unroll
        for (int j = 0; j < 4; ++j) {
            float v0 = ((float)a[2 * j]     + (float)c[2 * j])     * rl;
            float v1 = ((float)a[2 * j + 1] + (float)c[2 * j + 1]) * rl;
            pk[j] = (u32)f2bf(v0) | ((u32)f2bf(v1) << 16);
        }
        v.x = pk[0]; v.y = pk[1]; v.z = pk[2]; v.w = pk[3];
        size_t rowblk = ((size_t)(b * SEQ + q0) >> 4) + rb;
        *(uint4*)&AO[(rowblk * 32 + (h * 2 + kt2)) * 512 + lane * 8] = v;
    }
}

extern "C" void kernel_launch(void* const* d_in, const int* in_sizes, int n_in,
                              void* d_out, int out_size, void* d_ws, size_t ws_size,
                              hipStream_t stream) {
    const float* x   = (const float*)d_in[0];
    const int*   pos = (const int*)d_in[1];
    float* out = (float*)d_out;

    u16* ws = (u16*)d_ws;
    const size_t MD = (size_t)MM * DM;
    const size_t DD = (size_t)DM * DM;
    u16* Xsh = ws;                        // shuffled X; dead after QKV -> reused as AOsh
    u16* Wsh = ws + MD;                   // 4 shuffled weights (q,k,v,o)
    u16* Qbf = ws + MD + 4 * DD;          // Q natural bf16
    u16* Kfb = Qbf + MD;                  // K as QK-A-fragment chunks
    u16* VtB = Kfb + MD;                  // f16 V as PV-A-fragment chunks
    float2* ropetab = (float2*)(VtB + MD);
    _Float16* Vt = (_Float16*)VtB;
    u16* AOsh = Xsh;
    // split-k partials in DEDICATED workspace past all live buffers (ws ~268MB):
    // Lpart f32 512x128 (256KB) then Opart f16 512x(128x64) (8.4MB)
    float* Lpart = (float*)(ropetab + SEQ * 32);
    _Float16* Opart = (_Float16*)(Lpart + 512 * 128);

    // prep: bf16 shuffled X + 4 W, RoPE table (one launch)
    prep_kernel<<<dim3(128, 16), 256, 0, stream>>>(
        x, (const float*)d_in[2], (const float*)d_in[3], (const float*)d_in[4],
        (const float*)d_in[5], Xsh, Wsh, pos, ropetab);

    // Q/K/V projections, per-z blocks (z = blockIdx.z), 128x128 tiles, 3 blocks/CU;
    // counted-vmcnt triple-buffer K-loop; RoPE fused on Q,K; K/V written pre-fragmented
    gemm_s<4, false><<<dim3(32, 8, 3), 256, 0, stream>>>(
        Xsh, Wsh, Qbf, nullptr, Vt, Kfb, ropetab);

    // causal flash attention, split-k (768 balanced items, max 8 iters; splits write partials)
    attn_kernel<<<dim3(768), 256, 0, stream>>>(Qbf, Kfb, Vt, AOsh, Opart, Lpart);

    // combine split-k partials into AO
    combine_kernel<<<dim3(256), 256, 0, stream>>>(Opart, Lpart, AOsh);

    // output projection -> fp32 d_out (64x128 tiles, 2 blocks/CU)
    gemm_s<2, true><<<dim3(64, 8, 1), 256, 0, stream>>>(
        AOsh, Wsh + 3 * DD, nullptr, out, nullptr, nullptr, ropetab);
}